// Round 6
// baseline (1270.509 us; speedup 1.0000x reference)
//
#include <hip/hip_runtime.h>
#include <math.h>

#define HD 64   // H == F == 64
#define GD 50   // num gaussians
#define EPW 64  // edges per wave
#define WPB 2   // waves per block

__device__ __forceinline__ float ssp_f(float x) {
    // shifted softplus: softplus(x) - ln2, stable form max(x,0)+log(1+exp(-|x|))
    float ax = __builtin_fabsf(x);
    float e  = __expf(-ax);
    float sp = fmaxf(x, 0.0f) + __logf(1.0f + e);
    return sp - 0.69314718055994531f;
}

// xs = x @ l1w : [N,64]; also zero agg. gridDim.y selects edge-type t.
__global__ void __launch_bounds__(256) xs_kernel(
        const float* __restrict__ xA, const float* __restrict__ xB,
        const float* __restrict__ wA, const float* __restrict__ wB,
        float* __restrict__ xsA, float* __restrict__ xsB,
        float* __restrict__ aggA, float* __restrict__ aggB,
        int NA, int NB) {
    const int t = blockIdx.y;
    const float* x   = t ? xB : xA;
    const float* w   = t ? wB : wA;
    float* xs  = t ? xsB : xsA;
    float* agg = t ? aggB : aggA;
    const int N = t ? NB : NA;

    int wv = threadIdx.x >> 6;
    int j  = threadIdx.x & 63;
    int n  = blockIdx.x * 4 + wv;
    __shared__ float xr[4][64];
    if (n < N) xr[wv][j] = x[(size_t)n * HD + j];
    __syncthreads();
    if (n >= N) return;
    float acc = 0.0f;
#pragma unroll
    for (int k = 0; k < HD; ++k)
        acc = fmaf(xr[wv][k], w[k * HD + j], acc);
    xs[(size_t)n * HD + j] = acc;
    agg[(size_t)n * HD + j] = 0.0f;
}

// Per-edge filter MLP + modulate + scatter. Barrier-free restructure:
//   Each WAVE owns one 2048-float (8KB) LDS region used 3x sequentially:
//     (1) park h[32..63] lane-major, XOR-swizzled (4*(q^(lane&7))) -> no pad,
//         conflict-free b128; (2)+(3) two 32-edge x 64-ch w-buffers for the
//         scatter. No __syncthreads anywhere: all LDS RAW/WAR hazards are
//         same-wave (DS pipe is in-order per wave; lgkmcnt(0) fences added).
//   Scatter: lane = channel; per edge one FULL 256B contiguous xs-row read +
//   one FULL 256B contiguous atomic row (R0-measured: full-row atomics showed
//   zero atomic-RMW HBM fetch vs 400MB for split 128B rows). src/dst come via
//   __shfl(reg, const) -> v_readlane -> SGPR base addressing; sdst/ssrc LDS
//   arrays deleted. LDS/block 16384 -> 10 blocks/CU; waves fully decoupled.
__global__ void __launch_bounds__(WPB * 64, 2) edge_kernel(
        const float* __restrict__ eaA, const float* __restrict__ eaB,
        const float* __restrict__ ewA, const float* __restrict__ ewB,
        const int* __restrict__ eiA, const int* __restrict__ eiB,
        const float* __restrict__ xsA, const float* __restrict__ xsB,
        float* __restrict__ aggA, float* __restrict__ aggB,
        const float* __restrict__ mw1, const float* __restrict__ mb1,
        const float* __restrict__ mw2, const float* __restrict__ mb2,
        int EA, int EB) {
    const int ty = blockIdx.y;
    const float* ea = ty ? eaB : eaA;
    const float* ew = ty ? ewB : ewA;
    const int*   ei = ty ? eiB : eiA;
    const float* xs = ty ? xsB : xsA;
    float*      agg = ty ? aggB : aggA;
    const int E = ty ? EB : EA;

    const int wv   = threadIdx.x >> 6;
    const int lane = threadIdx.x & 63;
    const long ebase = ((long)blockIdx.x * WPB + wv) * EPW;

    __shared__ float wbuf[WPB][EPW * 32];   // 8 KB per wave
    float* wb = wbuf[wv];

    if (ebase >= (long)E) return;           // whole-wave guard (waves decoupled)

    long e = ebase + lane;
    bool valid = e < (long)E;
    long ec = valid ? e : (long)E - 1;

    int srcR = ei[ec];
    int dstR = ei[(size_t)E + ec];
    float cw = 0.5f * (__cosf(ew[ec] * 0.31415926535897931f) + 1.0f);
    if (!valid) cw = 0.0f;                  // invalid edges scatter zeros

    // ---- layer 1: h = ea_row @ mw1 + mb1 (h static-indexed -> VGPRs) ----
    const float2* ear2 = (const float2*)(ea + ec * GD);
    float h[HD];
#pragma unroll
    for (int f = 0; f < HD; ++f) h[f] = mb1[f];
    {
        float2 v = ear2[0];
        for (int gc = 0; gc < GD / 2; ++gc) {   // 25 iters; next load hidden under FMAs
            int gn = gc + 1 < GD / 2 ? gc + 1 : GD / 2 - 1;
            float2 vn = ear2[gn];
            const float* wr = mw1 + 2 * gc * HD;
#pragma unroll
            for (int f = 0; f < HD; ++f) h[f] = fmaf(v.x, wr[f], h[f]);
#pragma unroll
            for (int f = 0; f < HD; ++f) h[f] = fmaf(v.y, wr[HD + f], h[f]);
            v = vn;
        }
    }

    // ---- park h[32..63]: lane-major, XOR-swizzled b128 (conflict-free) ----
    {
        float* pr = wb + lane * 32;
        const int sw = lane & 7;
#pragma unroll
        for (int q = 0; q < 8; ++q)
            *(float4*)(pr + 4 * (q ^ sw)) =
                make_float4(h[32 + 4*q], h[32 + 4*q + 1],
                            h[32 + 4*q + 2], h[32 + 4*q + 3]);
    }
    asm volatile("s_waitcnt lgkmcnt(0)" ::: "memory");   // park visible before readback

    float w[HD];
#pragma unroll
    for (int j = 0; j < HD; ++j) w[j] = mb2[j];

    // ---- layer 2 part A: g in [0,32) from registers (fully unrolled) ----
#pragma unroll
    for (int gb = 0; gb < 8; ++gb) {
        float s0 = ssp_f(h[4*gb + 0]);
        float s1 = ssp_f(h[4*gb + 1]);
        float s2 = ssp_f(h[4*gb + 2]);
        float s3 = ssp_f(h[4*gb + 3]);
        const float* wr = mw2 + 4 * gb * HD;
#pragma unroll
        for (int j = 0; j < HD; ++j) w[j] = fmaf(s0, wr[j], w[j]);
#pragma unroll
        for (int j = 0; j < HD; ++j) w[j] = fmaf(s1, wr[HD + j], w[j]);
#pragma unroll
        for (int j = 0; j < HD; ++j) w[j] = fmaf(s2, wr[2 * HD + j], w[j]);
#pragma unroll
        for (int j = 0; j < HD; ++j) w[j] = fmaf(s3, wr[3 * HD + j], w[j]);
    }

    // ---- layer 2 part B: g in [32,64) from swizzled park (prefetched) ----
    {
        float* pr = wb + lane * 32;
        const int sw = lane & 7;
        float4 hv = *(const float4*)(pr + 4 * (0 ^ sw));
        for (int gb = 0; gb < 8; ++gb) {
            int gn = gb + 1 < 8 ? gb + 1 : 7;
            float4 hn = *(const float4*)(pr + 4 * (gn ^ sw));
            float s0 = ssp_f(hv.x), s1 = ssp_f(hv.y), s2 = ssp_f(hv.z), s3 = ssp_f(hv.w);
            const float* wr = mw2 + (32 + 4 * gb) * HD;
#pragma unroll
            for (int j = 0; j < HD; ++j) w[j] = fmaf(s0, wr[j], w[j]);
#pragma unroll
            for (int j = 0; j < HD; ++j) w[j] = fmaf(s1, wr[HD + j], w[j]);
#pragma unroll
            for (int j = 0; j < HD; ++j) w[j] = fmaf(s2, wr[2 * HD + j], w[j]);
#pragma unroll
            for (int j = 0; j < HD; ++j) w[j] = fmaf(s3, wr[3 * HD + j], w[j]);
            hv = hn;
        }
    }

    // ---- scatter: two 32-edge half-batches, full-row (256B) atomics ----
#pragma unroll
    for (int hb = 0; hb < 2; ++hb) {
        // lanes of this half write their w-row (x cw) swizzled into wbuf
        if ((lane >> 5) == hb) {
            const int r  = lane & 31;
            const int sw = r & 7;
            float* row = wb + r * HD;
#pragma unroll
            for (int q = 0; q < 16; ++q)
                *(float4*)(row + 4 * (q ^ sw)) =
                    make_float4(w[4*q] * cw,     w[4*q + 1] * cw,
                                w[4*q + 2] * cw, w[4*q + 3] * cw);
        }
        asm volatile("s_waitcnt lgkmcnt(0)" ::: "memory");   // rows visible (same wave)

        // lane = channel; per edge: 256B xs row read + 256B atomic row
#pragma unroll
        for (int k = 0; k < 32; ++k) {
            const int et = hb * 32 + k;
            int s = __shfl(srcR, et);        // v_readlane -> SGPR
            int d = __shfl(dstR, et);
            float xv = xs[(size_t)s * HD + lane];
            float wk = wb[k * HD + (lane ^ ((k & 7) << 2))];
            atomicAdd(&agg[(size_t)d * HD + lane], xv * wk);
        }
        asm volatile("s_waitcnt lgkmcnt(0)" ::: "memory");   // reads drained before overwrite
    }
}

// out = ssp(agg @ l2w + l2b) @ lin_w + lin_b. gridDim.y selects edge type.
__global__ void __launch_bounds__(256) out_kernel(
        const float* __restrict__ aggA, const float* __restrict__ aggB,
        const float* __restrict__ l2wA, const float* __restrict__ l2wB,
        const float* __restrict__ l2bA, const float* __restrict__ l2bB,
        const float* __restrict__ lw, const float* __restrict__ lb,
        float* __restrict__ outA, float* __restrict__ outB,
        int NA, int NB) {
    const int t = blockIdx.y;
    const float* agg = t ? aggB : aggA;
    const float* l2w = t ? l2wB : l2wA;
    const float* l2b = t ? l2bB : l2bA;
    float* out = t ? outB : outA;
    const int N = t ? NB : NA;

    int wv = threadIdx.x >> 6;
    int j  = threadIdx.x & 63;
    int n  = blockIdx.x * 4 + wv;
    __shared__ float buf[4][64];
    bool ok = n < N;
    if (ok) buf[wv][j] = agg[(size_t)n * HD + j];
    __syncthreads();
    float h = l2b[j];
#pragma unroll
    for (int g = 0; g < HD; ++g)
        h = fmaf(buf[wv][g], l2w[g * HD + j], h);
    h = ssp_f(h);
    __syncthreads();
    buf[wv][j] = h;
    __syncthreads();
    float o = lb[j];
#pragma unroll
    for (int g = 0; g < HD; ++g)
        o = fmaf(buf[wv][g], lw[g * HD + j], o);
    if (ok) out[(size_t)n * HD + j] = o;
}

extern "C" void kernel_launch(void* const* d_in, const int* in_sizes, int n_in,
                              void* d_out, int out_size, void* d_ws, size_t ws_size,
                              hipStream_t stream) {
    const float* x0   = (const float*)d_in[0];
    const float* x1   = (const float*)d_in[1];
    const int*   ei0  = (const int*)d_in[2];
    const int*   ei1  = (const int*)d_in[3];
    const float* ew0  = (const float*)d_in[4];
    const float* ew1  = (const float*)d_in[5];
    const float* ea0  = (const float*)d_in[6];
    const float* ea1  = (const float*)d_in[7];
    const float* mw1  = (const float*)d_in[8];
    const float* mb1  = (const float*)d_in[9];
    const float* mw2  = (const float*)d_in[10];
    const float* mb2  = (const float*)d_in[11];
    const float* l1w0 = (const float*)d_in[12];
    const float* l2w0 = (const float*)d_in[13];
    const float* l2b0 = (const float*)d_in[14];
    const float* l1w1 = (const float*)d_in[15];
    const float* l2w1 = (const float*)d_in[16];
    const float* l2b1 = (const float*)d_in[17];
    const float* lw   = (const float*)d_in[18];
    const float* lb   = (const float*)d_in[19];

    int N0 = in_sizes[0] / HD;
    int N1 = in_sizes[1] / HD;
    int E0 = in_sizes[4];
    int E1 = in_sizes[5];
    float* out = (float*)d_out;
    float* out0 = out;
    float* out1 = out + (size_t)N0 * HD;

    int Nmax = N0 > N1 ? N0 : N1;
    int Emax = E0 > E1 ? E0 : E1;
    int nodeBlocks = (Nmax + 3) / 4;
    int edgeBlocks = (Emax + WPB * EPW - 1) / (WPB * EPW);

    size_t needMerged = (size_t)(N0 + N1) * HD * 2 * sizeof(float);

    if (ws_size >= needMerged) {
        // merged path: 3 dispatches, gridDim.y = 2
        float* xs0  = (float*)d_ws;
        float* xs1  = xs0 + (size_t)N0 * HD;
        float* agg0 = xs1 + (size_t)N1 * HD;
        float* agg1 = agg0 + (size_t)N0 * HD;

        xs_kernel<<<dim3(nodeBlocks, 2), 256, 0, stream>>>(
            x0, x1, l1w0, l1w1, xs0, xs1, agg0, agg1, N0, N1);
        edge_kernel<<<dim3(edgeBlocks, 2), WPB * 64, 0, stream>>>(
            ea0, ea1, ew0, ew1, ei0, ei1, xs0, xs1, agg0, agg1,
            mw1, mb1, mw2, mb2, E0, E1);
        out_kernel<<<dim3(nodeBlocks, 2), 256, 0, stream>>>(
            agg0, agg1, l2w0, l2w1, l2b0, l2b1, lw, lb, out0, out1, N0, N1);
    } else {
        // fallback: sequential t-loop sharing one xs/agg buffer
        float* xs  = (float*)d_ws;
        float* agg = xs + (size_t)Nmax * HD;
        for (int t = 0; t < 2; ++t) {
            const float* x   = t ? x1 : x0;
            const int*   ei  = t ? ei1 : ei0;
            const float* ewp = t ? ew1 : ew0;
            const float* eap = t ? ea1 : ea0;
            const float* l1w = t ? l1w1 : l1w0;
            const float* l2w = t ? l2w1 : l2w0;
            const float* l2b = t ? l2b1 : l2b0;
            int N = t ? N1 : N0;
            int E = t ? E1 : E0;
            float* outp = t ? out1 : out0;
            int nb = (N + 3) / 4;
            int eb = (E + WPB * EPW - 1) / (WPB * EPW);
            xs_kernel<<<dim3(nb, 1), 256, 0, stream>>>(
                x, x, l1w, l1w, xs, xs, agg, agg, N, N);
            edge_kernel<<<dim3(eb, 1), WPB * 64, 0, stream>>>(
                eap, eap, ewp, ewp, ei, ei, xs, xs, agg, agg,
                mw1, mb1, mw2, mb2, E, E);
            out_kernel<<<dim3(nb, 1), 256, 0, stream>>>(
                agg, agg, l2w, l2w, l2b, l2b, lw, lb, outp, outp, N, N);
        }
    }
}